// Round 13
// baseline (541.447 us; speedup 1.0000x reference)
//
#include <hip/hip_runtime.h>
#include <hip/hip_bf16.h>

#define D 64
#define N_USERS 100000
#define N_ITEMS 50000
#define N_ENT   200000
#define EPS 1e-12f
#define CHUNK 4096
#define NBIN  391   // bins per sort (all three modes)
#define NBINP 512
#define CAP   8192  // max edges per bin for LDS-staged pass 2

typedef unsigned short u16;
typedef unsigned int u32;
typedef unsigned long long u64;

__device__ __forceinline__ float bf2f(u16 u) {
  return __uint_as_float(((unsigned)u) << 16);
}
__device__ __forceinline__ u16 f2bf(float f) {
  unsigned u = __float_as_uint(f);
  unsigned r = (u + 0x7FFFu + ((u >> 16) & 1u)) >> 16;  // RNE
  return (u16)r;
}
__device__ __forceinline__ float wave_rsqnorm(float v) {
  float ss = v * v;
#pragma unroll
  for (int m = 1; m < 64; m <<= 1) ss += __shfl_xor(ss, m);
  return 1.f / fmaxf(sqrtf(ss), EPS);
}
// lane-constant broadcast on the VALU (v_readlane), NOT the LDS pipe
__device__ __forceinline__ float bcast(float v, int k) {
  return __uint_as_float(__builtin_amdgcn_readlane(__float_as_uint(v), k));
}

// ==================== bf16 conversion of input tables =======================
__global__ __launch_bounds__(256) void conv_embed(
    const float* __restrict__ ent, const float* __restrict__ usr,
    u16* __restrict__ ent_bf, u16* __restrict__ usr_bf) {
  int i = blockIdx.x * 256 + threadIdx.x;
  if (i < N_ENT * D) ent_bf[i] = f2bf(ent[i]);
  if (i < N_USERS * D) usr_bf[i] = f2bf(usr[i]);
}

// ====== build step A: bin histograms, mode-partitioned blocks (4K keys) =====
__global__ __launch_bounds__(256) void hist_part(
    const int* __restrict__ head, int n_edges, int nbh_kg,
    const int* __restrict__ mcol, const int* __restrict__ mrow, int n_inter,
    int nbh_in, int* __restrict__ tot) {
  int mode, blk, shift, n;
  const int* keys;
  if ((int)blockIdx.x < nbh_kg) {
    mode = 0; blk = blockIdx.x; shift = 9; keys = head; n = n_edges;
  } else if ((int)blockIdx.x < nbh_kg + nbh_in) {
    mode = 1; blk = blockIdx.x - nbh_kg; shift = 7; keys = mcol; n = n_inter;
  } else {
    mode = 2; blk = blockIdx.x - nbh_kg - nbh_in; shift = 8; keys = mrow;
    n = n_inter;
  }
  __shared__ int h[NBINP];
  int tid = threadIdx.x;
  h[tid] = 0; h[tid + 256] = 0;
  __syncthreads();
  int base = blk * CHUNK;
  int end = min(base + CHUNK, n);
  for (int i = base + tid; i < end; i += 256)
    atomicAdd(&h[keys[i] >> shift], 1);
  __syncthreads();
  int* t = tot + mode * 392;
  for (int b = tid; b < NBIN; b += 256)
    if (h[b]) atomicAdd(&t[b], h[b]);
}

// ========== build step B: scan 3x391 bin totals -> bases + cursors ==========
__global__ __launch_bounds__(512) void scan_bases(
    const int* __restrict__ tot, int* __restrict__ bases,
    int* __restrict__ cur, int n0, int n1, int n2) {
  __shared__ int sm[512];
  int tid = threadIdx.x;
  for (int s = 0; s < 3; ++s) {
    int tn = (s == 0) ? n0 : ((s == 1) ? n1 : n2);
    int v = (tid < NBIN) ? tot[s * 392 + tid] : 0;
    __syncthreads();
    sm[tid] = v;
    __syncthreads();
    for (int ofs = 1; ofs < 512; ofs <<= 1) {
      int t = (tid >= ofs) ? sm[tid - ofs] : 0;
      __syncthreads();
      sm[tid] += t;
      __syncthreads();
    }
    if (tid < NBIN) {
      int b = sm[tid] - v;  // exclusive
      bases[s * 392 + tid] = b;
      cur[s * 392 + tid] = b;
    }
    if (tid == 0) bases[s * 392 + NBIN] = tn;  // sentinel
  }
}

// == build step C: binned scatter (atomic range reservation + LDS staging) ===
__global__ __launch_bounds__(256) void p1_all(
    const int* __restrict__ head, const int* __restrict__ tail,
    const int* __restrict__ etype, int n_edges, int nb_kg,
    const int* __restrict__ mcol, const int* __restrict__ mrow, int n_inter,
    int nb_c, int* __restrict__ cur_all,
    int2* __restrict__ bin_head, int2* __restrict__ bin_col,
    int2* __restrict__ bin_row) {
  int mode, blk, shift, n;
  const int* keys; const int* pa; const int* pb;
  int* cur; int2* out;
  if ((int)blockIdx.x < nb_kg) {
    mode = 0; blk = blockIdx.x; shift = 9; keys = head; pa = tail; pb = etype;
    n = n_edges; cur = cur_all; out = bin_head;
  } else if ((int)blockIdx.x < nb_kg + nb_c) {
    mode = 1; blk = blockIdx.x - nb_kg; shift = 7; keys = mcol; pa = mrow;
    pb = nullptr; n = n_inter; cur = cur_all + 392; out = bin_col;
  } else {
    mode = 2; blk = blockIdx.x - nb_kg - nb_c; shift = 8; keys = mrow;
    pa = mcol; pb = nullptr; n = n_inter; cur = cur_all + 784; out = bin_row;
  }
  __shared__ int h[NBINP];
  __shared__ int bb[NBINP];
  __shared__ int lcur[NBINP];
  __shared__ int2 staged[CHUNK];
  int tid = threadIdx.x;
  h[tid] = 0; h[tid + 256] = 0;
  __syncthreads();
  int base = blk * CHUNK;
  int end = min(base + CHUNK, n);
  for (int i = base + tid; i < end; i += 256)
    atomicAdd(&h[keys[i] >> shift], 1);
  __syncthreads();
  int o0 = h[tid], o1 = h[tid + 256];
  for (int ofs = 1; ofs < NBINP; ofs <<= 1) {  // inclusive Hillis-Steele
    int v0 = (tid >= ofs) ? h[tid - ofs] : 0;
    int v1 = (tid + 256 >= ofs) ? h[tid + 256 - ofs] : 0;
    __syncthreads();
    h[tid] += v0; h[tid + 256] += v1;
    __syncthreads();
  }
  int e0 = h[tid] - o0, e1 = h[tid + 256] - o1;  // exclusive local offsets
  lcur[tid] = e0; lcur[tid + 256] = e1;
  if (tid < NBIN && o0 > 0)       bb[tid] = atomicAdd(&cur[tid], o0) - e0;
  if (tid + 256 < NBIN && o1 > 0) bb[tid + 256] = atomicAdd(&cur[tid + 256], o1) - e1;
  __syncthreads();
  for (int i = base + tid; i < end; i += 256) {
    int k = keys[i];
    int payload;
    if (mode == 0) payload = pa[i] | (pb[i] << 24);
    else           payload = pa[i];
    int lp = atomicAdd(&lcur[k >> shift], 1);
    staged[lp] = make_int2(k, payload);
  }
  __syncthreads();
  int cnt = end - base;
  for (int t = tid; t < cnt; t += 256) {  // coalesced bin-run write-out
    int2 e = staged[t];
    out[bb[e.x >> shift] + t] = e;
  }
}

// ==== pass 2: in-bin sort -> payload + per-edge seg id (one launch) =========
__global__ __launch_bounds__(256) void p2_all(
    const int2* __restrict__ bin_head, const int2* __restrict__ bin_col,
    const int2* __restrict__ bin_row, const int* __restrict__ bases_all,
    int* __restrict__ pk_head, int* __restrict__ hid_h,
    int* __restrict__ vr_col, int* __restrict__ hid_c,
    int* __restrict__ vc_row, int* __restrict__ hid_r) {
  int mode = blockIdx.x / NBIN;
  int b = blockIdx.x - mode * NBIN;
  int shift = (mode == 0) ? 9 : ((mode == 1) ? 7 : 8);
  const int2* binned = (mode == 0) ? bin_head : ((mode == 1) ? bin_col : bin_row);
  const int* bases = bases_all + mode * 392;
  int* vals = (mode == 0) ? pk_head : ((mode == 1) ? vr_col : vc_row);
  int* hids = (mode == 0) ? hid_h : ((mode == 1) ? hid_c : hid_r);
  __shared__ int h[NBINP];
  __shared__ int cur[NBINP];
  __shared__ int staged[CAP];
  int tid = threadIdx.x;
  int start = bases[b];
  int endp = bases[b + 1];
  int cnt = endp - start;
  h[tid] = 0; h[tid + 256] = 0;
  __syncthreads();
  int segbase = b << shift;
  for (int t = tid; t < cnt; t += 256)
    atomicAdd(&h[binned[start + t].x - segbase], 1);
  __syncthreads();
  int o0 = h[tid], o1 = h[tid + 256];
  for (int ofs = 1; ofs < NBINP; ofs <<= 1) {
    int v0 = (tid >= ofs) ? h[tid - ofs] : 0;
    int v1 = (tid + 256 >= ofs) ? h[tid + 256 - ofs] : 0;
    __syncthreads();
    h[tid] += v0; h[tid + 256] += v1;
    __syncthreads();
  }
  int e0 = h[tid] - o0, e1 = h[tid + 256] - o1;  // exclusive
  cur[tid] = e0; cur[tid + 256] = e1;
  __syncthreads();
  if (cnt <= CAP) {
    for (int t = tid; t < cnt; t += 256) {
      int2 e = binned[start + t];
      int lp = atomicAdd(&cur[e.x - segbase], 1);
      staged[lp] = e.y;
      hids[start + lp] = e.x;  // small-range scatter (L2-resident window)
    }
    __syncthreads();
    for (int t = tid; t < cnt; t += 256) vals[start + t] = staged[t];
  } else {  // overflow fallback: correct, scattered
    for (int t = tid; t < cnt; t += 256) {
      int2 e = binned[start + t];
      int lp = atomicAdd(&cur[e.x - segbase], 1);
      vals[start + lp] = e.y;
      hids[start + lp] = e.x;
    }
  }
}

// ================ edge-parallel gather, 2 dims/lane =========================
// One wave per 64 consecutive sorted edges. Lane layout: pi = lane&31 is the
// bf16-PAIR index (dims 2pi, 2pi+1); half = lane>>5 processes even/odd edges
// in lockstep pairs. Segment boundaries (wave-uniform emit mask) flush with a
// cross-half shfl_xor(32) combine. Interior segments -> float2 store from
// half 0; window-spanning -> 2x atomicAdd. ~3 VALU/edge vs ~7 for 1-dim/lane.
template<bool REL>
__device__ __forceinline__ void eg_window2(
    const u32* __restrict__ tab2, const float2* lds_relw2,
    const int* __restrict__ pk, const int* __restrict__ hid,
    float* __restrict__ raw, int n, int win, int lane) {
  int S = win * 64;
  if (S >= n) return;
  float2* raw2 = (float2*)raw;
  int pi = lane & 31, half = lane >> 5;
  int cnt = min(64, n - S);
  int p  = (S + lane < n) ? pk[S + lane]  : 0;
  int hd = (S + lane < n) ? hid[S + lane] : -3;
  int hp = (S > 0) ? hid[S - 1] : -4;
  int hn = (S + 64 < n) ? hid[S + 64] : -5;
  int hnl = __shfl_down(hd, 1);
  if (lane == 63) hnl = hn;
  u64 real = __ballot(hd != hnl);
  if (cnt < 64) real &= (1ull << cnt) - 1ull;
  u64 emit = real | (1ull << (cnt - 1));  // always emit at window end
  bool start_in = (__shfl(hd, 0) != hp);
  float ax = 0.f, ay = 0.f;

  auto flush = [&](int j) {
    float fx = ax + __shfl_xor(ax, 32);
    float fy = ay + __shfl_xor(ay, 32);
    int h = __shfl(hd, j);
    if (start_in && ((real >> j) & 1ull)) {
      if (half == 0) raw2[(size_t)h * 32 + pi] = make_float2(fx, fy);
    } else if (half == 0) {
      atomicAdd(&raw[(size_t)h * D + 2 * pi], fx);
      atomicAdd(&raw[(size_t)h * D + 2 * pi + 1], fy);
    }
    ax = 0.f; ay = 0.f;
    start_in = true;
  };

  if (cnt == 64) {
    for (int sb = 0; sb < 32; sb += 8) {  // 8 edge-pairs = 16 edges per block
      u32 rv[8]; float2 rw[8];
#pragma unroll
      for (int k = 0; k < 8; ++k) {
        int j = 2 * (sb + k) + half;
        int q = __shfl(p, j);
        rv[k] = tab2[(size_t)(q & 0xFFFFFF) * 32 + pi];
        if (REL) rw[k] = lds_relw2[((((unsigned)q) >> 24) << 5) + pi];
      }
      u64 m16 = (emit >> (2 * sb)) & 0xFFFFull;
      if (m16 == 0) {  // fast path: no segment ends in these 16 edges
#pragma unroll
        for (int k = 0; k < 8; ++k) {
          float cx = bf2f((u16)(rv[k] & 0xFFFF));
          float cy = bf2f((u16)(rv[k] >> 16));
          if (REL) { cx *= rw[k].x; cy *= rw[k].y; }
          ax += cx; ay += cy;
        }
      } else {
#pragma unroll
        for (int k = 0; k < 8; ++k) {
          int j0 = 2 * (sb + k);           // even edge (half 0's edge)
          float cx = bf2f((u16)(rv[k] & 0xFFFF));
          float cy = bf2f((u16)(rv[k] >> 16));
          if (REL) { cx *= rw[k].x; cy *= rw[k].y; }
          bool e0 = (emit >> j0) & 1ull;
          bool e1 = (emit >> (j0 + 1)) & 1ull;
          if (!e0 && !e1) {
            ax += cx; ay += cy;
          } else {
            if (e0) {
              if (half == 0) { ax += cx; ay += cy; }  // edge j0 in segment
              flush(j0);
              if (half == 1) { ax = cx; ay = cy; }    // edge j0+1 -> next seg
            } else {
              ax += cx; ay += cy;
            }
            if (e1) flush(j0 + 1);
          }
        }
      }
    }
  } else {  // partial tail window (n % 64 != 0 only)
    for (int s = 0; 2 * s < cnt; ++s) {
      int j = 2 * s + half;
      float cx = 0.f, cy = 0.f;
      if (j < cnt) {
        int q = __shfl(p, j);
        u32 rv = tab2[(size_t)(q & 0xFFFFFF) * 32 + pi];
        cx = bf2f((u16)(rv & 0xFFFF));
        cy = bf2f((u16)(rv >> 16));
        if (REL) {
          float2 rw = lds_relw2[((((unsigned)q) >> 24) << 5) + pi];
          cx *= rw.x; cy *= rw.y;
        }
      }
      int j0 = 2 * s;
      bool e0 = (emit >> j0) & 1ull;
      bool e1 = (j0 + 1 < cnt) && ((emit >> (j0 + 1)) & 1ull);
      if (!e0 && !e1) {
        ax += cx; ay += cy;
      } else {
        if (e0) {
          if (half == 0) { ax += cx; ay += cy; }
          flush(j0);
          if (half == 1) { ax = cx; ay = cy; }
        } else {
          ax += cx; ay += cy;
        }
        if (e1) flush(j0 + 1);
      }
    }
  }
}

// ============ per-hop: KG gather + item<-user gather in ONE launch ==========
__global__ __launch_bounds__(256) void hop_gathers(
    const u16* __restrict__ ein, const float* __restrict__ relw,
    const int* __restrict__ pk_head, const int* __restrict__ hid_h,
    float* __restrict__ ent_raw, int n_edges, int kg_blocks,
    const u16* __restrict__ uin, const int* __restrict__ vr_col,
    const int* __restrict__ hid_c, float* __restrict__ iu, int n_inter) {
  __shared__ float2 lds_relw2[32 * 32];
  int lane = threadIdx.x & 63;
  int wave = threadIdx.x >> 6;
  if ((int)blockIdx.x < kg_blocks) {
    const float2* rw2 = (const float2*)relw;
    for (int i = threadIdx.x; i < 32 * 32; i += 256) lds_relw2[i] = rw2[i];
    __syncthreads();
    eg_window2<true>((const u32*)ein, lds_relw2, pk_head, hid_h, ent_raw,
                     n_edges, blockIdx.x * 4 + wave, lane);
  } else {
    eg_window2<false>((const u32*)uin, nullptr, vr_col, hid_c, iu, n_inter,
                      (blockIdx.x - kg_blocks) * 4 + wave, lane);
  }
}

// ===== gate GEMM + fusion, 4 rows per wave (LDS reads amortized 4x) =========
__global__ __launch_bounds__(256) void fuse_items(
    const float* __restrict__ ent_raw, const float* __restrict__ iu,
    const float* __restrict__ relw, const float* __restrict__ g1,
    const float* __restrict__ g2, u16* __restrict__ fus_bf,
    u16* __restrict__ ent_out) {
  __shared__ float G1[D][D + 1];
  __shared__ float G2[D][D + 1];
  for (int i = threadIdx.x; i < D * D; i += 256) {
    G1[i >> 6][i & 63] = g1[i];
    G2[i >> 6][i & 63] = g2[i];
  }
  __syncthreads();
  int wave = threadIdx.x >> 6;
  int lane = threadIdx.x & 63;
  int row0 = (blockIdx.x * 4 + wave) * 4;
  if (row0 >= N_ITEMS) return;
  float rw = relw[lane];
  float eav[4], uv[4], s1[4], s2[4];
#pragma unroll
  for (int i = 0; i < 4; ++i) {
    size_t o = (size_t)(row0 + i) * D + lane;
    eav[i] = ent_raw[o];
    uv[i] = iu[o] * rw;
    s1[i] = 0.f; s2[i] = 0.f;
  }
#pragma unroll
  for (int k = 0; k < D; ++k) {
    float ga = G1[lane][k], gb = G2[lane][k];
#pragma unroll
    for (int i = 0; i < 4; ++i) {
      s1[i] += bcast(eav[i], k) * ga;
      s2[i] += bcast(uv[i], k) * gb;
    }
  }
#pragma unroll
  for (int i = 0; i < 4; ++i) {
    size_t o = (size_t)(row0 + i) * D + lane;
    float s = s1[i] + s2[i];
    float gi = s > 0.f ? s : 0.2f * s;
    float fus = gi * eav[i] + (1.f - gi) * uv[i];
    fus_bf[o] = f2bf(fus);  // raw fusion (user gather input)
    float nv = fus * wave_rsqnorm(fus);
    ent_out[o] = f2bf(nv);
  }
}

// ===== finalize non-item entity rows ∥ user gather, one launch ==============
__global__ __launch_bounds__(256) void fin_and_user(
    const float* __restrict__ ent_raw, u16* __restrict__ eout, int nfin_blocks,
    const u16* __restrict__ fus_bf, const int* __restrict__ vc_row,
    const int* __restrict__ hid_r, float* __restrict__ usr_raw, int n_inter) {
  int wave = threadIdx.x >> 6;
  int lane = threadIdx.x & 63;
  if ((int)blockIdx.x < nfin_blocks) {
    int r = blockIdx.x * 4 + wave;
    if (r >= N_ENT - N_ITEMS) return;
    size_t o = (size_t)(N_ITEMS + r) * D + lane;
    float v = ent_raw[o];
    float nv = v * wave_rsqnorm(v);
    eout[o] = f2bf(nv);
  } else {
    eg_window2<false>((const u32*)fus_bf, nullptr, vc_row, hid_r, usr_raw,
                      n_inter, (blockIdx.x - nfin_blocks) * 4 + wave, lane);
  }
}

// ===================== finalize users: normalize ============================
__global__ __launch_bounds__(256) void fin_users(
    const float* __restrict__ raw, u16* __restrict__ out_bf) {
  int r = blockIdx.x * 4 + (threadIdx.x >> 6);
  if (r >= N_USERS) return;
  int lane = threadIdx.x & 63;
  size_t o = (size_t)r * D + lane;
  float v = raw[o];
  float nv = v * wave_rsqnorm(v);
  out_bf[o] = f2bf(nv);
}

// ============= final combine: out = input + hop1 + hop2 =====================
__global__ __launch_bounds__(256) void final_combine(
    const float* __restrict__ ent0, const float* __restrict__ usr0,
    const u16* __restrict__ e1, const u16* __restrict__ e2,
    const u16* __restrict__ u1, const u16* __restrict__ u2,
    float* __restrict__ out_ent, float* __restrict__ out_usr, int two) {
  int i = blockIdx.x * 256 + threadIdx.x;
  if (i < N_ENT * D) {
    float v = ent0[i] + bf2f(e1[i]);
    if (two) v += bf2f(e2[i]);
    out_ent[i] = v;
  }
  if (i < N_USERS * D) {
    float v = usr0[i] + bf2f(u1[i]);
    if (two) v += bf2f(u2[i]);
    out_usr[i] = v;
  }
}

// ============================ launch ========================================
extern "C" void kernel_launch(void* const* d_in, const int* in_sizes, int n_in,
                              void* d_out, int out_size, void* d_ws, size_t ws_size,
                              hipStream_t stream) {
  const float* user_emb = (const float*)d_in[0];
  const float* ent_emb  = (const float*)d_in[1];
  const float* relw     = (const float*)d_in[2];
  const float* g1       = (const float*)d_in[3];
  const float* g2       = (const float*)d_in[4];
  const int*   head     = (const int*)d_in[5];
  const int*   tail     = (const int*)d_in[6];
  const int*   etype    = (const int*)d_in[7];
  const int*   mrow     = (const int*)d_in[8];
  const int*   mcol     = (const int*)d_in[9];

  const int n_edges = in_sizes[5];
  const int n_inter = in_sizes[8];
  const int n_hops  = in_sizes[3] / (D * D);

  // ---- workspace carve (ws: tables + indices) ----
  u16* entA = (u16*)d_ws;
  u16* entB = entA + (size_t)N_ENT * D;
  u16* usrA = entB + (size_t)N_ENT * D;
  u16* usrB = usrA + (size_t)N_USERS * D;
  u16* fus_bf = usrB + (size_t)N_USERS * D;
  float* usr_raw = (float*)(fus_bf + (size_t)N_ITEMS * D);
  int* ip = (int*)(usr_raw + (size_t)N_USERS * D);
  int* pk_head = ip;  ip += n_edges;   // packed tail|etype<<24, head-grouped
  int* hid_h   = ip;  ip += n_edges;   // head id per sorted edge
  int* vr_col  = ip;  ip += n_inter;   // mrow grouped by col
  int* hid_c   = ip;  ip += n_inter;
  int* vc_row  = ip;  ip += n_inter;   // mcol grouped by row
  int* hid_r   = ip;  ip += n_inter;
  int* tot     = ip;  ip += 392 * 3;
  int* bases   = ip;  ip += 392 * 3;
  int* cur     = ip;  ip += 392 * 3;

  // ---- d_out doubles as scratch: bins (build) then raw accum (hops) ----
  float* ent_raw = (float*)d_out;                       // 51.2 MB
  float* iu      = ent_raw + (size_t)N_ENT * D;         // 12.8 MB
  int2* bin_head = (int2*)d_out;                        // build-phase only
  int2* bin_col  = bin_head + n_edges;
  int2* bin_row  = bin_col + n_inter;
  float* out_ent = (float*)d_out;                       // final only
  float* out_usr = out_ent + (size_t)N_ENT * D;

  // ---- build ----
  hipMemsetAsync(tot, 0, 392 * 3 * sizeof(int), stream);
  int nbh_kg = (n_edges + CHUNK - 1) / CHUNK;
  int nbh_in = (n_inter + CHUNK - 1) / CHUNK;
  hist_part<<<nbh_kg + 2 * nbh_in, 256, 0, stream>>>(
      head, n_edges, nbh_kg, mcol, mrow, n_inter, nbh_in, tot);
  scan_bases<<<1, 512, 0, stream>>>(tot, bases, cur, n_edges, n_inter, n_inter);

  p1_all<<<nbh_kg + 2 * nbh_in, 256, 0, stream>>>(
      head, tail, etype, n_edges, nbh_kg, mcol, mrow, n_inter, nbh_in,
      cur, bin_head, bin_col, bin_row);
  p2_all<<<3 * NBIN, 256, 0, stream>>>(
      bin_head, bin_col, bin_row, bases,
      pk_head, hid_h, vr_col, hid_c, vc_row, hid_r);

  conv_embed<<<(N_ENT * D + 255) / 256, 256, 0, stream>>>(
      ent_emb, user_emb, entA, usrA);

  const int nwin_kg = (n_edges + 63) / 64;
  const int nwin_in = (n_inter + 63) / 64;
  const int kg_blocks = (nwin_kg + 3) / 4;
  const int in_blocks = (nwin_in + 3) / 4;
  const int nfin_blocks = (N_ENT - N_ITEMS + 3) / 4;
  u16* etab[2] = {entA, entB};
  u16* utab[2] = {usrA, usrB};

  for (int i = 0; i < n_hops; ++i) {
    const u16* ein = etab[i & 1];
    u16* eout      = etab[(i + 1) & 1];
    const u16* uin = utab[i & 1];
    u16* uout      = utab[(i + 1) & 1];

    // zero raw accumulators up front (iu/usr_raw not read before gathers)
    hipMemsetAsync(ent_raw, 0,
                   (size_t)(N_ENT + N_ITEMS) * D * sizeof(float), stream);
    hipMemsetAsync(usr_raw, 0, (size_t)N_USERS * D * sizeof(float), stream);

    hop_gathers<<<kg_blocks + in_blocks, 256, 0, stream>>>(
        ein, relw, pk_head, hid_h, ent_raw, n_edges, kg_blocks,
        uin, vr_col, hid_c, iu, n_inter);

    fuse_items<<<(N_ITEMS + 15) / 16, 256, 0, stream>>>(
        ent_raw, iu, relw, g1 + (size_t)i * D * D, g2 + (size_t)i * D * D,
        fus_bf, eout);

    fin_and_user<<<nfin_blocks + in_blocks, 256, 0, stream>>>(
        ent_raw, eout, nfin_blocks, fus_bf, vc_row, hid_r, usr_raw, n_inter);

    fin_users<<<(N_USERS + 3) / 4, 256, 0, stream>>>(usr_raw, uout);
  }

  // out = input + hop1_table (+ hop2_table). (problem instance: n_hops = 2)
  const u16* e1 = etab[1];
  const u16* u1 = utab[1];
  const u16* e2 = (n_hops >= 2) ? etab[0] : etab[1];
  const u16* u2 = (n_hops >= 2) ? utab[0] : utab[1];
  final_combine<<<(N_ENT * D + 255) / 256, 256, 0, stream>>>(
      ent_emb, user_emb, e1, e2, u1, u2, out_ent, out_usr,
      (n_hops >= 2) ? 1 : 0);
}

// Round 14
// 527.868 us; speedup vs baseline: 1.0257x; 1.0257x over previous
//
#include <hip/hip_runtime.h>
#include <hip/hip_bf16.h>

#define D 64
#define N_USERS 100000
#define N_ITEMS 50000
#define N_ENT   200000
#define EPS 1e-12f
#define CHUNK 4096
#define NBIN  391   // bins per sort (all three modes)
#define NBINP 512
#define CAP   8192  // max edges per bin for LDS-staged pass 2

typedef unsigned short u16;
typedef unsigned int u32;
typedef unsigned long long u64;

__device__ __forceinline__ float bf2f(u16 u) {
  return __uint_as_float(((unsigned)u) << 16);
}
__device__ __forceinline__ u16 f2bf(float f) {
  unsigned u = __float_as_uint(f);
  unsigned r = (u + 0x7FFFu + ((u >> 16) & 1u)) >> 16;  // RNE
  return (u16)r;
}
__device__ __forceinline__ float wave_rsqnorm(float v) {
  float ss = v * v;
#pragma unroll
  for (int m = 1; m < 64; m <<= 1) ss += __shfl_xor(ss, m);
  return 1.f / fmaxf(sqrtf(ss), EPS);
}
// lane-constant broadcast on the VALU (v_readlane), NOT the LDS pipe
__device__ __forceinline__ float bcast(float v, int k) {
  return __uint_as_float(__builtin_amdgcn_readlane(__float_as_uint(v), k));
}

// ==================== bf16 conversion of input tables =======================
__global__ __launch_bounds__(256) void conv_embed(
    const float* __restrict__ ent, const float* __restrict__ usr,
    u16* __restrict__ ent_bf, u16* __restrict__ usr_bf) {
  int i = blockIdx.x * 256 + threadIdx.x;
  if (i < N_ENT * D) ent_bf[i] = f2bf(ent[i]);
  if (i < N_USERS * D) usr_bf[i] = f2bf(usr[i]);
}

// ====== build step A: bin histograms, mode-partitioned blocks (4K keys) =====
__global__ __launch_bounds__(256) void hist_part(
    const int* __restrict__ head, int n_edges, int nbh_kg,
    const int* __restrict__ mcol, const int* __restrict__ mrow, int n_inter,
    int nbh_in, int* __restrict__ tot) {
  int mode, blk, shift, n;
  const int* keys;
  if ((int)blockIdx.x < nbh_kg) {
    mode = 0; blk = blockIdx.x; shift = 9; keys = head; n = n_edges;
  } else if ((int)blockIdx.x < nbh_kg + nbh_in) {
    mode = 1; blk = blockIdx.x - nbh_kg; shift = 7; keys = mcol; n = n_inter;
  } else {
    mode = 2; blk = blockIdx.x - nbh_kg - nbh_in; shift = 8; keys = mrow;
    n = n_inter;
  }
  __shared__ int h[NBINP];
  int tid = threadIdx.x;
  h[tid] = 0; h[tid + 256] = 0;
  __syncthreads();
  int base = blk * CHUNK;
  int end = min(base + CHUNK, n);
  for (int i = base + tid; i < end; i += 256)
    atomicAdd(&h[keys[i] >> shift], 1);
  __syncthreads();
  int* t = tot + mode * 392;
  for (int b = tid; b < NBIN; b += 256)
    if (h[b]) atomicAdd(&t[b], h[b]);
}

// ========== build step B: scan 3x391 bin totals -> bases + cursors ==========
__global__ __launch_bounds__(512) void scan_bases(
    const int* __restrict__ tot, int* __restrict__ bases,
    int* __restrict__ cur, int n0, int n1, int n2) {
  __shared__ int sm[512];
  int tid = threadIdx.x;
  for (int s = 0; s < 3; ++s) {
    int tn = (s == 0) ? n0 : ((s == 1) ? n1 : n2);
    int v = (tid < NBIN) ? tot[s * 392 + tid] : 0;
    __syncthreads();
    sm[tid] = v;
    __syncthreads();
    for (int ofs = 1; ofs < 512; ofs <<= 1) {
      int t = (tid >= ofs) ? sm[tid - ofs] : 0;
      __syncthreads();
      sm[tid] += t;
      __syncthreads();
    }
    if (tid < NBIN) {
      int b = sm[tid] - v;  // exclusive
      bases[s * 392 + tid] = b;
      cur[s * 392 + tid] = b;
    }
    if (tid == 0) bases[s * 392 + NBIN] = tn;  // sentinel
  }
}

// == build step C: binned scatter (atomic range reservation + LDS staging) ===
__global__ __launch_bounds__(256) void p1_all(
    const int* __restrict__ head, const int* __restrict__ tail,
    const int* __restrict__ etype, int n_edges, int nb_kg,
    const int* __restrict__ mcol, const int* __restrict__ mrow, int n_inter,
    int nb_c, int* __restrict__ cur_all,
    int2* __restrict__ bin_head, int2* __restrict__ bin_col,
    int2* __restrict__ bin_row) {
  int mode, blk, shift, n;
  const int* keys; const int* pa; const int* pb;
  int* cur; int2* out;
  if ((int)blockIdx.x < nb_kg) {
    mode = 0; blk = blockIdx.x; shift = 9; keys = head; pa = tail; pb = etype;
    n = n_edges; cur = cur_all; out = bin_head;
  } else if ((int)blockIdx.x < nb_kg + nb_c) {
    mode = 1; blk = blockIdx.x - nb_kg; shift = 7; keys = mcol; pa = mrow;
    pb = nullptr; n = n_inter; cur = cur_all + 392; out = bin_col;
  } else {
    mode = 2; blk = blockIdx.x - nb_kg - nb_c; shift = 8; keys = mrow;
    pa = mcol; pb = nullptr; n = n_inter; cur = cur_all + 784; out = bin_row;
  }
  __shared__ int h[NBINP];
  __shared__ int bb[NBINP];
  __shared__ int lcur[NBINP];
  __shared__ int2 staged[CHUNK];
  int tid = threadIdx.x;
  h[tid] = 0; h[tid + 256] = 0;
  __syncthreads();
  int base = blk * CHUNK;
  int end = min(base + CHUNK, n);
  for (int i = base + tid; i < end; i += 256)
    atomicAdd(&h[keys[i] >> shift], 1);
  __syncthreads();
  int o0 = h[tid], o1 = h[tid + 256];
  for (int ofs = 1; ofs < NBINP; ofs <<= 1) {  // inclusive Hillis-Steele
    int v0 = (tid >= ofs) ? h[tid - ofs] : 0;
    int v1 = (tid + 256 >= ofs) ? h[tid + 256 - ofs] : 0;
    __syncthreads();
    h[tid] += v0; h[tid + 256] += v1;
    __syncthreads();
  }
  int e0 = h[tid] - o0, e1 = h[tid + 256] - o1;  // exclusive local offsets
  lcur[tid] = e0; lcur[tid + 256] = e1;
  if (tid < NBIN && o0 > 0)       bb[tid] = atomicAdd(&cur[tid], o0) - e0;
  if (tid + 256 < NBIN && o1 > 0) bb[tid + 256] = atomicAdd(&cur[tid + 256], o1) - e1;
  __syncthreads();
  for (int i = base + tid; i < end; i += 256) {
    int k = keys[i];
    int payload;
    if (mode == 0) payload = pa[i] | (pb[i] << 24);
    else           payload = pa[i];
    int lp = atomicAdd(&lcur[k >> shift], 1);
    staged[lp] = make_int2(k, payload);
  }
  __syncthreads();
  int cnt = end - base;
  for (int t = tid; t < cnt; t += 256) {  // coalesced bin-run write-out
    int2 e = staged[t];
    out[bb[e.x >> shift] + t] = e;
  }
}

// ==== pass 2: in-bin sort -> payload + per-edge seg id (one launch) =========
__global__ __launch_bounds__(256) void p2_all(
    const int2* __restrict__ bin_head, const int2* __restrict__ bin_col,
    const int2* __restrict__ bin_row, const int* __restrict__ bases_all,
    int* __restrict__ pk_head, int* __restrict__ hid_h,
    int* __restrict__ vr_col, int* __restrict__ hid_c,
    int* __restrict__ vc_row, int* __restrict__ hid_r) {
  int mode = blockIdx.x / NBIN;
  int b = blockIdx.x - mode * NBIN;
  int shift = (mode == 0) ? 9 : ((mode == 1) ? 7 : 8);
  const int2* binned = (mode == 0) ? bin_head : ((mode == 1) ? bin_col : bin_row);
  const int* bases = bases_all + mode * 392;
  int* vals = (mode == 0) ? pk_head : ((mode == 1) ? vr_col : vc_row);
  int* hids = (mode == 0) ? hid_h : ((mode == 1) ? hid_c : hid_r);
  __shared__ int h[NBINP];
  __shared__ int cur[NBINP];
  __shared__ int staged[CAP];
  int tid = threadIdx.x;
  int start = bases[b];
  int endp = bases[b + 1];
  int cnt = endp - start;
  h[tid] = 0; h[tid + 256] = 0;
  __syncthreads();
  int segbase = b << shift;
  for (int t = tid; t < cnt; t += 256)
    atomicAdd(&h[binned[start + t].x - segbase], 1);
  __syncthreads();
  int o0 = h[tid], o1 = h[tid + 256];
  for (int ofs = 1; ofs < NBINP; ofs <<= 1) {
    int v0 = (tid >= ofs) ? h[tid - ofs] : 0;
    int v1 = (tid + 256 >= ofs) ? h[tid + 256 - ofs] : 0;
    __syncthreads();
    h[tid] += v0; h[tid + 256] += v1;
    __syncthreads();
  }
  int e0 = h[tid] - o0, e1 = h[tid + 256] - o1;  // exclusive
  cur[tid] = e0; cur[tid + 256] = e1;
  __syncthreads();
  if (cnt <= CAP) {
    for (int t = tid; t < cnt; t += 256) {
      int2 e = binned[start + t];
      int lp = atomicAdd(&cur[e.x - segbase], 1);
      staged[lp] = e.y;
      hids[start + lp] = e.x;  // small-range scatter (L2-resident window)
    }
    __syncthreads();
    for (int t = tid; t < cnt; t += 256) vals[start + t] = staged[t];
  } else {  // overflow fallback: correct, scattered
    for (int t = tid; t < cnt; t += 256) {
      int2 e = binned[start + t];
      int lp = atomicAdd(&cur[e.x - segbase], 1);
      vals[start + lp] = e.y;
      hids[start + lp] = e.x;
    }
  }
}

// ======================= edge-parallel gather (device fn) ===================
// One wave per 64 consecutive sorted edges (lane = dim). Loads always 8-deep;
// segment boundaries from a ballot mask. Interior segments -> plain row store
// into raw (f32, zeroed); window-spanning segments -> atomicAdd (~2/window).
template<bool REL>
__device__ __forceinline__ void eg_window(
    const u16* __restrict__ tab, const float* lds_relw,
    const int* __restrict__ pk, const int* __restrict__ hid,
    float* __restrict__ raw, int n, int win, int lane) {
  int S = win * 64;
  if (S >= n) return;
  int cnt = min(64, n - S);
  int p  = (S + lane < n) ? pk[S + lane]  : 0;
  int hd = (S + lane < n) ? hid[S + lane] : -3;
  int hp = (S > 0) ? hid[S - 1] : -4;
  int hn = (S + 64 < n) ? hid[S + 64] : -5;
  int hnl = __shfl_down(hd, 1);
  if (lane == 63) hnl = hn;
  u64 real = __ballot(hd != hnl);
  if (cnt < 64) real &= (1ull << cnt) - 1ull;
  u64 emit = real | (1ull << (cnt - 1));  // always emit at window end
  bool start_in = (__shfl(hd, 0) != hp);
  float acc = 0.f;
  if (cnt == 64) {
    for (int base = 0; base < 64; base += 8) {
      u16 r[8]; int et[8];
#pragma unroll
      for (int k = 0; k < 8; ++k) {
        int q = __shfl(p, base + k);
        if (REL) {
          r[k] = tab[(size_t)(q & 0xFFFFFF) * D + lane];
          et[k] = ((unsigned)q) >> 24;
        } else {
          r[k] = tab[(size_t)q * D + lane];
        }
      }
#pragma unroll
      for (int k = 0; k < 8; ++k) {
        int j = base + k;
        float c = bf2f(r[k]);
        if (REL) c *= lds_relw[et[k] * D + lane];
        acc += c;
        if ((emit >> j) & 1ull) {
          int h = __shfl(hd, j);
          float* dst = raw + (size_t)h * D + lane;
          if (start_in && ((real >> j) & 1ull)) *dst = acc;
          else atomicAdd(dst, acc);
          acc = 0.f;
          start_in = true;
        }
      }
    }
  } else {  // partial tail window
    for (int j = 0; j < cnt; ++j) {
      int q = __shfl(p, j);
      float c;
      if (REL) c = bf2f(tab[(size_t)(q & 0xFFFFFF) * D + lane]) *
                   lds_relw[(((unsigned)q) >> 24) * D + lane];
      else     c = bf2f(tab[(size_t)q * D + lane]);
      acc += c;
      if ((emit >> j) & 1ull) {
        int h = __shfl(hd, j);
        float* dst = raw + (size_t)h * D + lane;
        if (start_in && ((real >> j) & 1ull)) *dst = acc;
        else atomicAdd(dst, acc);
        acc = 0.f;
        start_in = true;
      }
    }
  }
}

// ============ per-hop: KG gather + item<-user gather in ONE launch ==========
__global__ __launch_bounds__(256) void hop_gathers(
    const u16* __restrict__ ein, const float* __restrict__ relw,
    const int* __restrict__ pk_head, const int* __restrict__ hid_h,
    float* __restrict__ ent_raw, int n_edges, int kg_blocks,
    const u16* __restrict__ uin, const int* __restrict__ vr_col,
    const int* __restrict__ hid_c, float* __restrict__ iu, int n_inter) {
  __shared__ float lds_relw[32 * D];
  int lane = threadIdx.x & 63;
  int wave = threadIdx.x >> 6;
  if ((int)blockIdx.x < kg_blocks) {
    for (int i = threadIdx.x; i < 32 * D; i += 256) lds_relw[i] = relw[i];
    __syncthreads();
    eg_window<true>(ein, lds_relw, pk_head, hid_h, ent_raw, n_edges,
                    blockIdx.x * 4 + wave, lane);
  } else {
    eg_window<false>(uin, nullptr, vr_col, hid_c, iu, n_inter,
                     (blockIdx.x - kg_blocks) * 4 + wave, lane);
  }
}

// ===== gate GEMM + fusion, 4 rows per wave (LDS reads amortized 4x) =========
__global__ __launch_bounds__(256) void fuse_items(
    const float* __restrict__ ent_raw, const float* __restrict__ iu,
    const float* __restrict__ relw, const float* __restrict__ g1,
    const float* __restrict__ g2, u16* __restrict__ fus_bf,
    u16* __restrict__ ent_out) {
  __shared__ float G1[D][D + 1];
  __shared__ float G2[D][D + 1];
  for (int i = threadIdx.x; i < D * D; i += 256) {
    G1[i >> 6][i & 63] = g1[i];
    G2[i >> 6][i & 63] = g2[i];
  }
  __syncthreads();
  int wave = threadIdx.x >> 6;
  int lane = threadIdx.x & 63;
  int row0 = (blockIdx.x * 4 + wave) * 4;
  if (row0 >= N_ITEMS) return;
  float rw = relw[lane];
  float eav[4], uv[4], s1[4], s2[4];
#pragma unroll
  for (int i = 0; i < 4; ++i) {
    size_t o = (size_t)(row0 + i) * D + lane;
    eav[i] = ent_raw[o];
    uv[i] = iu[o] * rw;
    s1[i] = 0.f; s2[i] = 0.f;
  }
#pragma unroll
  for (int k = 0; k < D; ++k) {
    float ga = G1[lane][k], gb = G2[lane][k];
#pragma unroll
    for (int i = 0; i < 4; ++i) {
      s1[i] += bcast(eav[i], k) * ga;
      s2[i] += bcast(uv[i], k) * gb;
    }
  }
#pragma unroll
  for (int i = 0; i < 4; ++i) {
    size_t o = (size_t)(row0 + i) * D + lane;
    float s = s1[i] + s2[i];
    float gi = s > 0.f ? s : 0.2f * s;
    float fus = gi * eav[i] + (1.f - gi) * uv[i];
    fus_bf[o] = f2bf(fus);  // raw fusion (user gather input)
    float nv = fus * wave_rsqnorm(fus);
    ent_out[o] = f2bf(nv);
  }
}

// ===== finalize non-item entity rows ∥ user gather, one launch ==============
__global__ __launch_bounds__(256) void fin_and_user(
    const float* __restrict__ ent_raw, u16* __restrict__ eout, int nfin_blocks,
    const u16* __restrict__ fus_bf, const int* __restrict__ vc_row,
    const int* __restrict__ hid_r, float* __restrict__ usr_raw, int n_inter) {
  int wave = threadIdx.x >> 6;
  int lane = threadIdx.x & 63;
  if ((int)blockIdx.x < nfin_blocks) {
    int r = blockIdx.x * 4 + wave;
    if (r >= N_ENT - N_ITEMS) return;
    size_t o = (size_t)(N_ITEMS + r) * D + lane;
    float v = ent_raw[o];
    float nv = v * wave_rsqnorm(v);
    eout[o] = f2bf(nv);
  } else {
    eg_window<false>(fus_bf, nullptr, vc_row, hid_r, usr_raw, n_inter,
                     (blockIdx.x - nfin_blocks) * 4 + wave, lane);
  }
}

// ===================== finalize users: normalize ============================
__global__ __launch_bounds__(256) void fin_users(
    const float* __restrict__ raw, u16* __restrict__ out_bf) {
  int r = blockIdx.x * 4 + (threadIdx.x >> 6);
  if (r >= N_USERS) return;
  int lane = threadIdx.x & 63;
  size_t o = (size_t)r * D + lane;
  float v = raw[o];
  float nv = v * wave_rsqnorm(v);
  out_bf[o] = f2bf(nv);
}

// ============= final combine: out = input + hop1 + hop2 =====================
__global__ __launch_bounds__(256) void final_combine(
    const float* __restrict__ ent0, const float* __restrict__ usr0,
    const u16* __restrict__ e1, const u16* __restrict__ e2,
    const u16* __restrict__ u1, const u16* __restrict__ u2,
    float* __restrict__ out_ent, float* __restrict__ out_usr, int two) {
  int i = blockIdx.x * 256 + threadIdx.x;
  if (i < N_ENT * D) {
    float v = ent0[i] + bf2f(e1[i]);
    if (two) v += bf2f(e2[i]);
    out_ent[i] = v;
  }
  if (i < N_USERS * D) {
    float v = usr0[i] + bf2f(u1[i]);
    if (two) v += bf2f(u2[i]);
    out_usr[i] = v;
  }
}

// ============================ launch ========================================
extern "C" void kernel_launch(void* const* d_in, const int* in_sizes, int n_in,
                              void* d_out, int out_size, void* d_ws, size_t ws_size,
                              hipStream_t stream) {
  const float* user_emb = (const float*)d_in[0];
  const float* ent_emb  = (const float*)d_in[1];
  const float* relw     = (const float*)d_in[2];
  const float* g1       = (const float*)d_in[3];
  const float* g2       = (const float*)d_in[4];
  const int*   head     = (const int*)d_in[5];
  const int*   tail     = (const int*)d_in[6];
  const int*   etype    = (const int*)d_in[7];
  const int*   mrow     = (const int*)d_in[8];
  const int*   mcol     = (const int*)d_in[9];

  const int n_edges = in_sizes[5];
  const int n_inter = in_sizes[8];
  const int n_hops  = in_sizes[3] / (D * D);

  // ---- workspace carve (ws: tables + indices) ----
  u16* entA = (u16*)d_ws;
  u16* entB = entA + (size_t)N_ENT * D;
  u16* usrA = entB + (size_t)N_ENT * D;
  u16* usrB = usrA + (size_t)N_USERS * D;
  u16* fus_bf = usrB + (size_t)N_USERS * D;
  float* usr_raw = (float*)(fus_bf + (size_t)N_ITEMS * D);
  int* ip = (int*)(usr_raw + (size_t)N_USERS * D);
  int* pk_head = ip;  ip += n_edges;   // packed tail|etype<<24, head-grouped
  int* hid_h   = ip;  ip += n_edges;   // head id per sorted edge
  int* vr_col  = ip;  ip += n_inter;   // mrow grouped by col
  int* hid_c   = ip;  ip += n_inter;
  int* vc_row  = ip;  ip += n_inter;   // mcol grouped by row
  int* hid_r   = ip;  ip += n_inter;
  int* tot     = ip;  ip += 392 * 3;
  int* bases   = ip;  ip += 392 * 3;
  int* cur     = ip;  ip += 392 * 3;

  // ---- d_out doubles as scratch: bins (build) then raw accum (hops) ----
  float* ent_raw = (float*)d_out;                       // 51.2 MB
  float* iu      = ent_raw + (size_t)N_ENT * D;         // 12.8 MB
  int2* bin_head = (int2*)d_out;                        // build-phase only
  int2* bin_col  = bin_head + n_edges;
  int2* bin_row  = bin_col + n_inter;
  float* out_ent = (float*)d_out;                       // final only
  float* out_usr = out_ent + (size_t)N_ENT * D;

  // ---- build ----
  hipMemsetAsync(tot, 0, 392 * 3 * sizeof(int), stream);
  int nbh_kg = (n_edges + CHUNK - 1) / CHUNK;
  int nbh_in = (n_inter + CHUNK - 1) / CHUNK;
  hist_part<<<nbh_kg + 2 * nbh_in, 256, 0, stream>>>(
      head, n_edges, nbh_kg, mcol, mrow, n_inter, nbh_in, tot);
  scan_bases<<<1, 512, 0, stream>>>(tot, bases, cur, n_edges, n_inter, n_inter);

  p1_all<<<nbh_kg + 2 * nbh_in, 256, 0, stream>>>(
      head, tail, etype, n_edges, nbh_kg, mcol, mrow, n_inter, nbh_in,
      cur, bin_head, bin_col, bin_row);
  p2_all<<<3 * NBIN, 256, 0, stream>>>(
      bin_head, bin_col, bin_row, bases,
      pk_head, hid_h, vr_col, hid_c, vc_row, hid_r);

  conv_embed<<<(N_ENT * D + 255) / 256, 256, 0, stream>>>(
      ent_emb, user_emb, entA, usrA);

  const int nwin_kg = (n_edges + 63) / 64;
  const int nwin_in = (n_inter + 63) / 64;
  const int kg_blocks = (nwin_kg + 3) / 4;
  const int in_blocks = (nwin_in + 3) / 4;
  const int nfin_blocks = (N_ENT - N_ITEMS + 3) / 4;
  u16* etab[2] = {entA, entB};
  u16* utab[2] = {usrA, usrB};

  for (int i = 0; i < n_hops; ++i) {
    const u16* ein = etab[i & 1];
    u16* eout      = etab[(i + 1) & 1];
    const u16* uin = utab[i & 1];
    u16* uout      = utab[(i + 1) & 1];

    // zero raw accumulators up front (iu/usr_raw not read before gathers)
    hipMemsetAsync(ent_raw, 0,
                   (size_t)(N_ENT + N_ITEMS) * D * sizeof(float), stream);
    hipMemsetAsync(usr_raw, 0, (size_t)N_USERS * D * sizeof(float), stream);

    hop_gathers<<<kg_blocks + in_blocks, 256, 0, stream>>>(
        ein, relw, pk_head, hid_h, ent_raw, n_edges, kg_blocks,
        uin, vr_col, hid_c, iu, n_inter);

    fuse_items<<<(N_ITEMS + 15) / 16, 256, 0, stream>>>(
        ent_raw, iu, relw, g1 + (size_t)i * D * D, g2 + (size_t)i * D * D,
        fus_bf, eout);

    fin_and_user<<<nfin_blocks + in_blocks, 256, 0, stream>>>(
        ent_raw, eout, nfin_blocks, fus_bf, vc_row, hid_r, usr_raw, n_inter);

    fin_users<<<(N_USERS + 3) / 4, 256, 0, stream>>>(usr_raw, uout);
  }

  // out = input + hop1_table (+ hop2_table). (problem instance: n_hops = 2)
  const u16* e1 = etab[1];
  const u16* u1 = utab[1];
  const u16* e2 = (n_hops >= 2) ? etab[0] : etab[1];
  const u16* u2 = (n_hops >= 2) ? utab[0] : utab[1];
  final_combine<<<(N_ENT * D + 255) / 256, 256, 0, stream>>>(
      ent_emb, user_emb, e1, e2, u1, u2, out_ent, out_usr,
      (n_hops >= 2) ? 1 : 0);
}